// Round 10
// baseline (3825.477 us; speedup 1.0000x reference)
//
#include <hip/hip_runtime.h>
#include <hip/hip_bf16.h>
#include <hip/hip_fp16.h>
#include <cstdint>
#include <cstddef>

typedef __attribute__((ext_vector_type(4))) float floatx4;
typedef __attribute__((ext_vector_type(8))) short shortx8;
typedef __attribute__((ext_vector_type(2))) __fp16 f16x2;
typedef __attribute__((ext_vector_type(8))) __fp16 halfx8;

#define T_SEQ 512
#define NIN   512
#define BATCH 256
#define HID   256
#define G3    768
#define NC    101

static __device__ __forceinline__ unsigned short f2bf(float f){
  unsigned int u = __float_as_uint(f);
  u += 0x7FFFu + ((u >> 16) & 1u);
  return (unsigned short)(u >> 16);
}

// ---------------- Phase A: xg[gm][gn] = x . Wih^T + bih (+ bhh folded for
// r,z gates). Natural row-major fp16 output (gm = b*Tc+tt, gn = gate-col).
#define BM 128
#define BN 128
#define BK 64
#define LDK 72

__global__ __launch_bounds__(256) void gemm_xg(
    const float* __restrict__ x, const float* __restrict__ Wih,
    const float* __restrict__ bih, const float* __restrict__ bhh,
    __fp16* __restrict__ xg, int t0, int tcLog2)
{
  __shared__ unsigned short As[BM*LDK];
  __shared__ unsigned short Bs[BN*LDK];
  const int tid  = threadIdx.x;
  const int bn   = blockIdx.x;   // N fastest: 6 consecutive blocks share one x-tile (L2 reuse)
  const int bm   = blockIdx.y;
  const int w    = tid >> 6;
  const int l    = tid & 63;
  const int lm   = l & 15;
  const int quad = l >> 4;

  const int srow = tid >> 4;
  const int scol = (tid & 15) * 4;
  const int tcMask = (1 << tcLog2) - 1;

  floatx4 acc[2][8];
  #pragma unroll
  for (int mt = 0; mt < 2; ++mt)
    #pragma unroll
    for (int nt = 0; nt < 8; ++nt)
      acc[mt][nt] = (floatx4){0.f, 0.f, 0.f, 0.f};

  for (int kt = 0; kt < NIN / BK; ++kt){
    const int k0 = kt * BK;
    __syncthreads();
    #pragma unroll
    for (int p = 0; p < 8; ++p){
      const int r  = p * 16 + srow;
      const int gm = bm * BM + r;
      const int b  = gm >> tcLog2;
      const int tt = gm & tcMask;
      const float4 xa = *(const float4*)(x + (size_t)(b * T_SEQ + t0 + tt) * NIN + k0 + scol);
      union { unsigned short u[4]; uint2 v; } pa;
      pa.u[0] = f2bf(xa.x); pa.u[1] = f2bf(xa.y); pa.u[2] = f2bf(xa.z); pa.u[3] = f2bf(xa.w);
      *(uint2*)&As[r * LDK + scol] = pa.v;
      const int gn = bn * BN + r;
      const float4 wb = *(const float4*)(Wih + (size_t)gn * NIN + k0 + scol);
      union { unsigned short u[4]; uint2 v; } pb;
      pb.u[0] = f2bf(wb.x); pb.u[1] = f2bf(wb.y); pb.u[2] = f2bf(wb.z); pb.u[3] = f2bf(wb.w);
      *(uint2*)&Bs[r * LDK + scol] = pb.v;
    }
    __syncthreads();
    #pragma unroll
    for (int ks = 0; ks < 2; ++ks){
      const int kk = ks * 32 + quad * 8;
      shortx8 af[2], bfr[8];
      #pragma unroll
      for (int mt = 0; mt < 2; ++mt)
        af[mt] = *(const shortx8*)&As[(w * 32 + mt * 16 + lm) * LDK + kk];
      #pragma unroll
      for (int nt = 0; nt < 8; ++nt)
        bfr[nt] = *(const shortx8*)&Bs[(nt * 16 + lm) * LDK + kk];
      #pragma unroll
      for (int mt = 0; mt < 2; ++mt)
        #pragma unroll
        for (int nt = 0; nt < 8; ++nt)
          acc[mt][nt] = __builtin_amdgcn_mfma_f32_16x16x32_bf16(af[mt], bfr[nt], acc[mt][nt], 0, 0, 0);
    }
  }

  #pragma unroll
  for (int mt = 0; mt < 2; ++mt){
    #pragma unroll
    for (int nt = 0; nt < 8; ++nt){
      #pragma unroll
      for (int i = 0; i < 4; ++i){
        const int ml = w * 32 + mt * 16 + quad * 4 + i;
        const int nl = nt * 16 + lm;
        const int gm = bm * BM + ml;
        const int gn = bn * BN + nl;
        float v = acc[mt][nt][i] + bih[gn];
        if (gn < 512) v += bhh[gn];            // fold bhh for r,z gates (exact)
        xg[(size_t)gm * G3 + gn] = (__fp16)v;
      }
    }
  }
}

// ---------------- Phase B: batched-MFMA GRU, 512 threads / 8 waves, with
// amdgpu_waves_per_eu(2,2): min=max=2 waves/SIMD PINS the register budget
// at 256/thread so the compiler cannot defect to 128 (R5/R7) or 64 (R9)
// and shred the W-resident array into AGPR/scratch shuttles.
// Wave w owns j-slice [32w, 32w+32) (2 subtiles of 16) x 3 gates:
// 6 acc tiles of mfma_f32_16x16x32_f16 (M=16 batches, K=256 in 8 steps).
// Demand: Bf 192 + acc 24 + xv 12 + hold 8 + addr ~15 = ~251 <= 256.
// h: f32 state in regs; f16 mirror in LDS, double-buffered, XOR-swizzled.
#define BB 16

__global__ __attribute__((amdgpu_flat_work_group_size(512, 512), amdgpu_waves_per_eu(2, 2)))
void gru_mfma(
    const __fp16* __restrict__ xg, const float* __restrict__ Whh,
    const float* __restrict__ bhh, float* __restrict__ hstate, int Tc)
{
  __shared__ __align__(16) __fp16 hls[2][BB * HID];
  const int tid = threadIdx.x;
  const int w   = tid >> 6;        // wave 0..7: j-slice
  const int l   = tid & 63;
  const int lm  = l & 15;          // A row (batch) on reads; D col (j)
  const int lq  = l >> 4;          // k-chunk selector; D rows = lq*4+i
  const int bb0 = blockIdx.x * BB;
  const int jb  = w * 32 + lm;     // j for js=0; js=1 adds +16
  const int hswz = (lm & 7) << 3;  // A-read swizzle (half units, keyed on A row)

  // B-frags: lane l holds W[g*256 + jb + js*16][ks*32 + lq*8 .. +7] (f16) = 192 VGPRs
  halfx8 Bf[3][2][8];
  #pragma unroll
  for (int g = 0; g < 3; ++g)
    #pragma unroll
    for (int js = 0; js < 2; ++js)
      #pragma unroll
      for (int ks = 0; ks < 8; ++ks){
        const float* wp = Whh + (size_t)(g * 256 + jb + js * 16) * HID + ks * 32 + lq * 8;
        const float4 v0 = *(const float4*)wp;
        const float4 v1 = *(const float4*)(wp + 4);
        union { f16x2 h[4]; halfx8 v; } u;
        u.h[0] = __builtin_amdgcn_cvt_pkrtz(v0.x, v0.y);
        u.h[1] = __builtin_amdgcn_cvt_pkrtz(v0.z, v0.w);
        u.h[2] = __builtin_amdgcn_cvt_pkrtz(v1.x, v1.y);
        u.h[3] = __builtin_amdgcn_cvt_pkrtz(v1.z, v1.w);
        Bf[g][js][ks] = u.v;
      }

  // Only n-gate bhh lives here (r,z folded into xg by gemm_xg).
  const float bn0 = bhh[512 + jb];
  const float bn1 = bhh[512 + jb + 16];

  // init h (f32 state in regs + f16 mirror in LDS buf 0); each (b,j) once
  float hold[2][4];
  #pragma unroll
  for (int js = 0; js < 2; ++js)
    #pragma unroll
    for (int i = 0; i < 4; ++i){
      const int b = lq * 4 + i;
      const int j = jb + js * 16;
      const float h0 = hstate[(bb0 + b) * HID + j];
      hold[js][i] = h0;
      hls[0][b * HID + (j ^ ((b & 7) << 3))] = (__fp16)h0;
    }

  // xg base pointers for this thread's 4 batch rows at column jb
  const __fp16* xp0 = xg + ((size_t)(bb0 + lq * 4 + 0) * Tc) * G3 + jb;
  const __fp16* xp1 = xg + ((size_t)(bb0 + lq * 4 + 1) * Tc) * G3 + jb;
  const __fp16* xp2 = xg + ((size_t)(bb0 + lq * 4 + 2) * Tc) * G3 + jb;
  const __fp16* xp3 = xg + ((size_t)(bb0 + lq * 4 + 3) * Tc) * G3 + jb;

  __syncthreads();

  #pragma unroll 1
  for (int t = 0; t < Tc; ++t){
    // 24 scalar u16 loads: issued here, consumed after the MFMA loop
    __fp16 xv[4][6];   // [i][gate*2+js]: offsets js*16 + gate*256
    {
      const __fp16* xp[4] = {xp0, xp1, xp2, xp3};
      #pragma unroll
      for (int i = 0; i < 4; ++i){
        xv[i][0] = xp[i][0];   xv[i][1] = xp[i][16];
        xv[i][2] = xp[i][256]; xv[i][3] = xp[i][272];
        xv[i][4] = xp[i][512]; xv[i][5] = xp[i][528];
      }
    }

    floatx4 acc[3][2];
    #pragma unroll
    for (int g = 0; g < 3; ++g)
      #pragma unroll
      for (int js = 0; js < 2; ++js)
        acc[g][js] = (floatx4){0.f, 0.f, 0.f, 0.f};

    const __fp16* hb = &hls[t & 1][0];
    const __fp16* p0 = hb + lm * HID + ((lq * 8) ^ hswz);
    const __fp16* p1 = hb + lm * HID + ((32 + lq * 8) ^ hswz);
    #pragma unroll
    for (int ks = 0; ks < 8; ++ks){
      const halfx8 av = *(const halfx8*)(((ks & 1) ? p1 : p0) + (ks >> 1) * 64);
      #pragma unroll
      for (int g = 0; g < 3; ++g)
        #pragma unroll
        for (int js = 0; js < 2; ++js)
          acc[g][js] = __builtin_amdgcn_mfma_f32_16x16x32_f16(av, Bf[g][js][ks], acc[g][js], 0, 0, 0);
    }

    __fp16* hbn = &hls[(t + 1) & 1][0];
    #pragma unroll
    for (int js = 0; js < 2; ++js){
      const float bnj = js ? bn1 : bn0;
      #pragma unroll
      for (int i = 0; i < 4; ++i){
        const float r = 1.f / (1.f + __expf(-((float)xv[i][js] + acc[0][js][i])));
        const float z = 1.f / (1.f + __expf(-((float)xv[i][2 + js] + acc[1][js][i])));
        const float a = (float)xv[i][4 + js] + r * (acc[2][js][i] + bnj);
        const float ex = __expf(-2.f * fabsf(a));
        float n = (1.f - ex) / (1.f + ex);
        n = copysignf(n, a);
        const float hnew = fmaf(z, hold[js][i] - n, n);   // (1-z)*n + z*h
        hold[js][i] = hnew;
        const int b = lq * 4 + i;
        const int j = jb + js * 16;
        hbn[b * HID + (j ^ ((b & 7) << 3))] = (__fp16)hnew;
      }
    }
    __syncthreads();
    xp0 += G3; xp1 += G3; xp2 += G3; xp3 += G3;
  }

  #pragma unroll
  for (int js = 0; js < 2; ++js)
    #pragma unroll
    for (int i = 0; i < 4; ++i)
      hstate[(bb0 + lq * 4 + i) * HID + jb + js * 16] = hold[js][i];
}

// ---------------- FC
__global__ __launch_bounds__(128) void fc_kernel(
    const float* __restrict__ hstate, const float* __restrict__ fw,
    const float* __restrict__ fb, float* __restrict__ out)
{
  __shared__ float hs[HID];
  const int b = blockIdx.x;
  const int t = threadIdx.x;
  hs[t]       = hstate[b * HID + t];
  hs[t + 128] = hstate[b * HID + t + 128];
  __syncthreads();
  if (t < NC){
    float acc = fb[t];
    const float4* w4 = (const float4*)(fw + (size_t)t * HID);
    const float4* h4 = (const float4*)hs;
    #pragma unroll
    for (int k = 0; k < 64; ++k){
      const float4 wv = w4[k];
      const float4 hv = h4[k];
      acc += wv.x * hv.x + wv.y * hv.y + wv.z * hv.z + wv.w * hv.w;
    }
    out[b * NC + t] = acc;
  }
}

extern "C" void kernel_launch(void* const* d_in, const int* in_sizes, int n_in,
                              void* d_out, int out_size, void* d_ws, size_t ws_size,
                              hipStream_t stream)
{
  const float* x   = (const float*)d_in[0];
  const float* Wih = (const float*)d_in[1];
  const float* Whh = (const float*)d_in[2];
  const float* bih = (const float*)d_in[3];
  const float* bhh = (const float*)d_in[4];
  const float* fcw = (const float*)d_in[5];
  const float* fcb = (const float*)d_in[6];
  float* out = (float*)d_out;

  float* hst = (float*)d_ws;
  const size_t hBytes = (size_t)BATCH * HID * sizeof(float);
  __fp16* xg = (__fp16*)((char*)d_ws + hBytes);

  const size_t perT = (size_t)BATCH * G3 * sizeof(__fp16);
  const size_t avail = (ws_size > hBytes) ? (ws_size - hBytes) : 0;
  int tcLog2 = 9;
  while (tcLog2 > 0 && perT * ((size_t)1 << tcLog2) > avail) --tcLog2;
  const int Tc = 1 << tcLog2;

  (void)hipMemsetAsync(hst, 0, hBytes, stream);
  for (int t0 = 0; t0 < T_SEQ; t0 += Tc){
    dim3 grid(6, 2 * Tc);
    gemm_xg<<<grid, 256, 0, stream>>>(x, Wih, bih, bhh, xg, t0, tcLog2);
    gru_mfma<<<BATCH / BB, 512, 0, stream>>>(xg, Whh, bhh, hst, Tc);
  }
  fc_kernel<<<BATCH, 128, 0, stream>>>(hst, fcw, fcb, out);
}

// Round 12
// 1272.125 us; speedup vs baseline: 3.0072x; 3.0072x over previous
//
#include <hip/hip_runtime.h>
#include <hip/hip_bf16.h>
#include <cstdint>
#include <cstddef>

typedef __attribute__((ext_vector_type(4))) float floatx4;
typedef __attribute__((ext_vector_type(8))) short shortx8;
typedef __attribute__((ext_vector_type(2))) __fp16 f16x2;

#define T_SEQ 512
#define NIN   512
#define BATCH 256
#define HID   256
#define G3    768
#define NC    101

static __device__ __forceinline__ unsigned short f2bf(float f){
  unsigned int u = __float_as_uint(f);
  u += 0x7FFFu + ((u >> 16) & 1u);
  return (unsigned short)(u >> 16);
}

static __device__ __forceinline__ float dot2acc(f16x2 w, f16x2 h, float acc){
#if __has_builtin(__builtin_amdgcn_fdot2)
  return __builtin_amdgcn_fdot2(w, h, acc, false);
#else
  return acc + (float)w[0]*(float)h[0] + (float)w[1]*(float)h[1];
#endif
}

// ---------------- Pre-pass: f32 -> bf16 (vectorized). One-time conversion so
// gemm staging does pure 16B copies instead of per-element f2bf VALU work.
__global__ __launch_bounds__(256) void cvt_bf16(
    const float* __restrict__ src, unsigned short* __restrict__ dst, int n4)
{
  int i = blockIdx.x * 256 + threadIdx.x;
  const int stride = gridDim.x * 256;
  for (; i < n4; i += stride){
    const float4 v = *(const float4*)(src + (size_t)i * 4);
    union { unsigned short u[4]; uint2 q; } p;
    p.u[0] = f2bf(v.x); p.u[1] = f2bf(v.y); p.u[2] = f2bf(v.z); p.u[3] = f2bf(v.w);
    *(uint2*)(dst + (size_t)i * 4) = p.q;
  }
}

// ---------------- Phase A: xg[b*Tc+tt][n] = x[b,t0+tt,:].Wih[n,:] + bih[n]
// Inputs pre-converted bf16; staging = plain 16B copies (no f2bf in loop).
// MFMA core / fragment layout / LDK padding / epilogue identical to the
// session-verified kernel. Output f32, natural row-major (R1-gru layout).
#define BM 128
#define BN 128
#define BK 64
#define LDK 72

__global__ __launch_bounds__(256) void gemm_xg(
    const unsigned short* __restrict__ xbf, const unsigned short* __restrict__ wbf,
    const float* __restrict__ bih, float* __restrict__ xg,
    int t0, int tcLog2)
{
  __shared__ unsigned short As[BM*LDK];
  __shared__ unsigned short Bs[BN*LDK];
  const int tid  = threadIdx.x;
  const int bn   = blockIdx.x;   // N fastest: 6 consecutive blocks share one x-tile (L2 reuse)
  const int bm   = blockIdx.y;
  const int w    = tid >> 6;
  const int l    = tid & 63;
  const int lm   = l & 15;
  const int quad = l >> 4;

  const int srow2 = tid >> 3;        // 0..31
  const int scol8 = (tid & 7) * 8;   // 0,8,..,56
  const int tcMask = (1 << tcLog2) - 1;

  floatx4 acc[2][8];
  #pragma unroll
  for (int mt = 0; mt < 2; ++mt)
    #pragma unroll
    for (int nt = 0; nt < 8; ++nt)
      acc[mt][nt] = (floatx4){0.f, 0.f, 0.f, 0.f};

  for (int kt = 0; kt < NIN / BK; ++kt){
    const int k0 = kt * BK;
    __syncthreads();
    #pragma unroll
    for (int p = 0; p < 4; ++p){
      const int r  = p * 32 + srow2;
      const int gm = bm * BM + r;
      const int b  = gm >> tcLog2;
      const int tt = gm & tcMask;
      *(uint4*)&As[r * LDK + scol8] =
          *(const uint4*)(xbf + (size_t)(b * T_SEQ + t0 + tt) * NIN + k0 + scol8);
      const int gn = bn * BN + r;
      *(uint4*)&Bs[r * LDK + scol8] =
          *(const uint4*)(wbf + (size_t)gn * NIN + k0 + scol8);
    }
    __syncthreads();
    #pragma unroll
    for (int ks = 0; ks < 2; ++ks){
      const int kk = ks * 32 + quad * 8;
      shortx8 af[2], bfr[8];
      #pragma unroll
      for (int mt = 0; mt < 2; ++mt)
        af[mt] = *(const shortx8*)&As[(w * 32 + mt * 16 + lm) * LDK + kk];
      #pragma unroll
      for (int nt = 0; nt < 8; ++nt)
        bfr[nt] = *(const shortx8*)&Bs[(nt * 16 + lm) * LDK + kk];
      #pragma unroll
      for (int mt = 0; mt < 2; ++mt)
        #pragma unroll
        for (int nt = 0; nt < 8; ++nt)
          acc[mt][nt] = __builtin_amdgcn_mfma_f32_16x16x32_bf16(af[mt], bfr[nt], acc[mt][nt], 0, 0, 0);
    }
  }

  #pragma unroll
  for (int mt = 0; mt < 2; ++mt){
    #pragma unroll
    for (int nt = 0; nt < 8; ++nt){
      #pragma unroll
      for (int i = 0; i < 4; ++i){
        const int ml = w * 32 + mt * 16 + quad * 4 + i;
        const int nl = nt * 16 + lm;
        const int gm = bm * BM + ml;
        const int gn = bn * BN + nl;
        xg[(size_t)gm * G3 + gn] = acc[mt][nt][i] + bih[gn];
      }
    }
  }
}

// ---------------- Phase B: sequential GRU, split-K lane pairs (R1 verbatim,
// measured 715 us). tid = 2*j + half. 96 VGPRs of f16 weights per thread
// (lives across the 128-arch/128-accum split; v_dot2 reads AGPRs directly —
// unlike MFMA, this costs nothing; R5-R10 proved the MFMA path shuttles).
// h mirror in LDS double-buffered (1 barrier/step), half1 region padded +16B.
#define HSTRIDE 280   // uint16 elems per buffer (256 + 8 pad + pad-to-16B)

__global__ __launch_bounds__(512, 2) void gru_steps(
    const float* __restrict__ xg, const float* __restrict__ Whh,
    const float* __restrict__ bhh, float* __restrict__ hstate, int Tc)
{
  __shared__ alignas(16) unsigned short hph[2][HSTRIDE];
  const int b    = blockIdx.x;
  const int tid  = threadIdx.x;
  const int j    = tid >> 1;
  const int half = tid & 1;
  const int jpos = j + (j >= 128 ? 8 : 0);   // +16B pad between halves

  f16x2 wrr[64], wrz[64], wrn[64];
  {
    const float4* r4 = (const float4*)(Whh + (size_t)j * HID + half * 128);
    const float4* z4 = (const float4*)(Whh + (size_t)(j + 256) * HID + half * 128);
    const float4* n4 = (const float4*)(Whh + (size_t)(j + 512) * HID + half * 128);
    #pragma unroll
    for (int k = 0; k < 32; ++k){
      float4 v = r4[k];
      wrr[2*k]   = __builtin_amdgcn_cvt_pkrtz(v.x, v.y);
      wrr[2*k+1] = __builtin_amdgcn_cvt_pkrtz(v.z, v.w);
    }
    #pragma unroll
    for (int k = 0; k < 32; ++k){
      float4 v = z4[k];
      wrz[2*k]   = __builtin_amdgcn_cvt_pkrtz(v.x, v.y);
      wrz[2*k+1] = __builtin_amdgcn_cvt_pkrtz(v.z, v.w);
    }
    #pragma unroll
    for (int k = 0; k < 32; ++k){
      float4 v = n4[k];
      wrn[2*k]   = __builtin_amdgcn_cvt_pkrtz(v.x, v.y);
      wrn[2*k+1] = __builtin_amdgcn_cvt_pkrtz(v.z, v.w);
    }
  }
  const float br = bhh[j];
  const float bz = bhh[j + 256];
  const float bn = bhh[j + 512];

  float hj = hstate[b * HID + j];
  if (half == 0){
    union { __fp16 f; unsigned short u; } cv;
    cv.f = (__fp16)hj;
    hph[0][jpos] = cv.u;
  }
  __syncthreads();

  const float* xgrow = xg + (size_t)b * Tc * G3 + j;
  float xr = xgrow[0], xz = xgrow[256], xn = xgrow[512];

  #pragma unroll 1
  for (int t = 0; t < Tc; ++t){
    const int tn = (t + 1 < Tc) ? (t + 1) : t;
    const float nxr = xgrow[(size_t)tn * G3];
    const float nxz = xgrow[(size_t)tn * G3 + 256];
    const float nxn = xgrow[(size_t)tn * G3 + 512];

    // Preload this thread's 64 h-pairs (272-B aligned region; 17 uint4 stride).
    const uint4* hp4 = (const uint4*)(&hph[t & 1][0]) + half * 17;
    uint4 hv[16];
    #pragma unroll
    for (int i = 0; i < 16; ++i) hv[i] = hp4[i];

    float ar = 0.f, az = 0.f, an = 0.f;
    #pragma unroll
    for (int i = 0; i < 16; ++i){
      union { unsigned int u; f16x2 h; } c0, c1, c2, c3;
      c0.u = hv[i].x; c1.u = hv[i].y; c2.u = hv[i].z; c3.u = hv[i].w;
      const int p = 4 * i;
      ar = dot2acc(wrr[p    ], c0.h, ar);
      az = dot2acc(wrz[p    ], c0.h, az);
      an = dot2acc(wrn[p    ], c0.h, an);
      ar = dot2acc(wrr[p + 1], c1.h, ar);
      az = dot2acc(wrz[p + 1], c1.h, az);
      an = dot2acc(wrn[p + 1], c1.h, an);
      ar = dot2acc(wrr[p + 2], c2.h, ar);
      az = dot2acc(wrz[p + 2], c2.h, az);
      an = dot2acc(wrn[p + 2], c2.h, an);
      ar = dot2acc(wrr[p + 3], c3.h, ar);
      az = dot2acc(wrz[p + 3], c3.h, az);
      an = dot2acc(wrn[p + 3], c3.h, an);
    }
    const float hr = ar + __shfl_xor(ar, 1, 64) + br;
    const float hz = az + __shfl_xor(az, 1, 64) + bz;
    const float hn = an + __shfl_xor(an, 1, 64) + bn;

    const float r = 1.f / (1.f + __expf(-(xr + hr)));
    const float z = 1.f / (1.f + __expf(-(xz + hz)));
    const float a = xn + r * hn;
    const float ex = __expf(-2.f * fabsf(a));
    float n = (1.f - ex) / (1.f + ex);
    n = copysignf(n, a);
    const float hnew = fmaf(z, hj - n, n);   // (1-z)*n + z*h

    hj = hnew;
    if (half == 0){
      union { __fp16 f; unsigned short u; } cv;
      cv.f = (__fp16)hj;
      hph[1 - (t & 1)][jpos] = cv.u;   // write other buffer: no race with reads
    }
    __syncthreads();                    // single barrier: new buffer visible
    xr = nxr; xz = nxz; xn = nxn;
  }

  if (half == 0) hstate[b * HID + j] = hj;
}

// ---------------- FC
__global__ __launch_bounds__(128) void fc_kernel(
    const float* __restrict__ hstate, const float* __restrict__ fw,
    const float* __restrict__ fb, float* __restrict__ out)
{
  __shared__ float hs[HID];
  const int b = blockIdx.x;
  const int t = threadIdx.x;
  hs[t]       = hstate[b * HID + t];
  hs[t + 128] = hstate[b * HID + t + 128];
  __syncthreads();
  if (t < NC){
    float acc = fb[t];
    const float4* w4 = (const float4*)(fw + (size_t)t * HID);
    const float4* h4 = (const float4*)hs;
    #pragma unroll
    for (int k = 0; k < 64; ++k){
      const float4 wv = w4[k];
      const float4 hv = h4[k];
      acc += wv.x * hv.x + wv.y * hv.y + wv.z * hv.z + wv.w * hv.w;
    }
    out[b * NC + t] = acc;
  }
}

extern "C" void kernel_launch(void* const* d_in, const int* in_sizes, int n_in,
                              void* d_out, int out_size, void* d_ws, size_t ws_size,
                              hipStream_t stream)
{
  const float* x   = (const float*)d_in[0];
  const float* Wih = (const float*)d_in[1];
  const float* Whh = (const float*)d_in[2];
  const float* bih = (const float*)d_in[3];
  const float* bhh = (const float*)d_in[4];
  const float* fcw = (const float*)d_in[5];
  const float* fcb = (const float*)d_in[6];
  float* out = (float*)d_out;

  // workspace layout: hstate | xbf (bf16 x) | wbf (bf16 Wih) | xg (f32)
  const size_t hBytes   = (size_t)BATCH * HID * sizeof(float);          // 256 KB
  const size_t xbfBytes = (size_t)BATCH * T_SEQ * NIN * 2;              // 134 MB
  const size_t wbfBytes = (size_t)G3 * NIN * 2;                         // 0.75 MB
  float* hst = (float*)d_ws;
  unsigned short* xbf = (unsigned short*)((char*)d_ws + hBytes);
  unsigned short* wbf = (unsigned short*)((char*)d_ws + hBytes + xbfBytes);
  float* xg = (float*)((char*)d_ws + hBytes + xbfBytes + wbfBytes);

  const size_t fixed = hBytes + xbfBytes + wbfBytes;
  const size_t perT  = (size_t)BATCH * G3 * sizeof(float);
  const size_t avail = (ws_size > fixed) ? (ws_size - fixed) : 0;
  int tcLog2 = 9;
  while (tcLog2 > 0 && perT * ((size_t)1 << tcLog2) > avail) --tcLog2;
  const int Tc = 1 << tcLog2;

  cvt_bf16<<<2048, 256, 0, stream>>>(x, xbf, BATCH * T_SEQ * NIN / 4);
  cvt_bf16<<<384, 256, 0, stream>>>(Wih, wbf, G3 * NIN / 4);
  (void)hipMemsetAsync(hst, 0, hBytes, stream);
  for (int t0 = 0; t0 < T_SEQ; t0 += Tc){
    dim3 grid(6, 2 * Tc);
    gemm_xg<<<grid, 256, 0, stream>>>(xbf, wbf, bih, xg, t0, tcLog2);
    gru_steps<<<BATCH, 512, 0, stream>>>(xg, Whh, bhh, hst, Tc);
  }
  fc_kernel<<<BATCH, 128, 0, stream>>>(hst, fcw, fcb, out);
}